// Round 5
// baseline (355.865 us; speedup 1.0000x reference)
//
#include <hip/hip_runtime.h>

// R17: (1) out[0:384]=tanh(h1) moved from k_gat2 (latency-bound gather) into
// GEMM4's A-staging (each h1b element staged exactly once; grid.y==1) —
// k_gat2 write traffic 45->14.4 MB. (2) k_cvt_all+k_cvt_t_all merged into one
// kernel; k_dinv folded into k_scan. 12 launches (was 14). Gather kernels
// otherwise VERBATIM R12 (proven); 64x128 GEMM tile + parallel scan kept (R16).

#define NN 20000
#define EE 320000
#define GATD 384
#define NH 6
#define OUTD 64
#define ODIM 576

typedef __bf16 bf16_8 __attribute__((ext_vector_type(8)));
typedef float f32_4 __attribute__((ext_vector_type(4)));

__device__ __forceinline__ float lrelu(float x, float s) { return x > 0.f ? x : s * x; }

__device__ __forceinline__ float loadf(const void* p, size_t i, int f32) {
  return f32 ? ((const float*)p)[i] : (float)((const __bf16*)p)[i];
}

// ---------- fused dtype probes ----------
struct ProbeArgs {
  const void* ptr[15];
  int cnt[15];
  int flagidx[15];
  const int* ei;
};
__global__ void k_probe_all(ProbeArgs a, int* __restrict__ flags) {
  __shared__ int cnt;
  if (threadIdx.x == 0) cnt = 0;
  __syncthreads();
  int b = blockIdx.x;
  if (b < 15) {
    const unsigned short* u = (const unsigned short*)a.ptr[b];
    int m = a.cnt[b] < 2048 ? a.cnt[b] : 2048;
    int c = 0;
    for (int i = threadIdx.x; i < m; i += 256) {
      float v = __uint_as_float(((unsigned int)u[i]) << 16);
      if (!(fabsf(v) < 1e4f)) c++;
    }
    if (c) atomicAdd(&cnt, c);
    __syncthreads();
    if (threadIdx.x == 0) flags[a.flagidx[b]] = (cnt > m / 16) ? 1 : 0;
  } else {
    int c = 0;
    for (int i = threadIdx.x; i < 1024; i += 256)
      if (a.ei[2 * i + 1] != 0) c++;
    if (c) atomicAdd(&cnt, c);
    __syncthreads();
    if (threadIdx.x == 0) flags[16] = (cnt <= 2) ? 1 : 0;
  }
}

// ---------- merged small conversions + weight cvt/transpose ----------
struct CvtSeg { const void* in; __bf16* out; int n; int flagidx; int blk0; };
struct CvtArgs { CvtSeg s[7]; };
struct TSeg { const void* in; __bf16* out; int R; int C; int flagidx; int blk0; };
struct TArgs { TSeg s[6]; };
__global__ void k_cvt_merged(CvtArgs ca, int ncvtblk, TArgs ta, const int* __restrict__ flags) {
  if ((int)blockIdx.x < ncvtblk) {
    int b = blockIdx.x;
    int k = 0;
    while (k + 1 < 7 && ca.s[k + 1].blk0 <= b) k++;
    const CvtSeg sg = ca.s[k];
    int i = (b - sg.blk0) * 256 + threadIdx.x;
    if (i >= sg.n) return;
    sg.out[i] = flags[sg.flagidx] ? (__bf16)((const float*)sg.in)[i] : ((const __bf16*)sg.in)[i];
    return;
  }
  __shared__ float t[32][33];
  int b = blockIdx.x - ncvtblk;
  int k = 0;
  while (k + 1 < 6 && ta.s[k + 1].blk0 <= b) k++;
  const TSeg sg = ta.s[k];
  int f32 = flags[sg.flagidx];
  int tpx = (sg.C + 31) >> 5;
  int lt = b - sg.blk0;
  int c0 = (lt % tpx) * 32, r0 = (lt / tpx) * 32;
  int tid = threadIdx.x;
  for (int idx = tid; idx < 1024; idx += 256) {
    int r = idx >> 5, c = idx & 31;
    if (r0 + r < sg.R && c0 + c < sg.C)
      t[r][c] = loadf(sg.in, (size_t)(r0 + r) * sg.C + (c0 + c), f32);
  }
  __syncthreads();
  for (int idx = tid; idx < 1024; idx += 256) {
    int r = idx >> 5, c = idx & 31;
    if (c0 + r < sg.C && r0 + c < sg.R)
      sg.out[(size_t)(c0 + r) * sg.R + (r0 + c)] = (__bf16)t[c][r];
  }
}

// ---------- CSR build ----------
__global__ void k_count(const int* __restrict__ ei, const void* __restrict__ ew,
                        const int* __restrict__ flags,
                        int* __restrict__ deg, float* __restrict__ wdeg) {
  int e = blockIdx.x * 256 + threadIdx.x;
  if (e >= EE) return;
  int sh = flags[16];
  int d = ei[(size_t)(EE + e) << sh];
  atomicAdd(&deg[d], 1);
  atomicAdd(&wdeg[d], loadf(ew, e, flags[2]));
}

// parallel scan + dinv tail (k_dinv folded in)
__global__ __launch_bounds__(256) void k_scan(const int* __restrict__ deg,
    const float* __restrict__ wdeg, int* __restrict__ rowstart,
    float* __restrict__ dg, float* __restrict__ da) {
  __shared__ int wsum[4];
  int t = threadIdx.x;
  const int per = (NN + 255) / 256;
  int lo = t * per; if (lo > NN) lo = NN;
  int hi = lo + per; if (hi > NN) hi = NN;
  int s = 0;
  for (int i = lo; i < hi; i++) s += deg[i];
  int lane = t & 63, wv = t >> 6;
  int run = s;
  for (int off = 1; off < 64; off <<= 1) {
    int u = __shfl_up(run, off);
    if (lane >= off) run += u;
  }
  if (lane == 63) wsum[wv] = run;
  __syncthreads();
  int wbase = 0;
#pragma unroll
  for (int w = 0; w < 4; w++) { int v = wsum[w]; if (w < wv) wbase += v; }
  int a = wbase + run - s;  // exclusive prefix for this thread's run
  for (int i = lo; i < hi; i++) { rowstart[i] = a; a += deg[i]; }
  if (t == 255) rowstart[NN] = a;
  // dinv (independent elementwise tail)
  for (int i = t; i < NN; i += 256) {
    float w = wdeg[i];
    dg[i] = rsqrtf(w + 1.0f);
    da[i] = w > 0.f ? rsqrtf(w) : 0.f;
  }
}

__global__ void k_fill(const int* __restrict__ ei, const void* __restrict__ ew,
                       const int* __restrict__ flags, const int* __restrict__ rowstart,
                       int* __restrict__ cursor,
                       int* __restrict__ csr_src, float* __restrict__ csr_w) {
  int e = blockIdx.x * 256 + threadIdx.x;
  if (e >= EE) return;
  int sh = flags[16];
  int d = ei[(size_t)(EE + e) << sh];
  int s = ei[(size_t)e << sh];
  int pos = rowstart[d] + atomicAdd(&cursor[d], 1);
  csr_src[pos] = s;
  csr_w[pos] = loadf(ew, e, flags[2]);
}

// ---------- MFMA GEMM: C[M][N] = A[M][K] * Bt[N][K]^T (+bias), bf16 out ----------
// 64x128 block tile (acc[4][2]). Dual-output epilogue (n1 % 128 == 0).
// tout != nullptr (requires gridDim.y==1): while staging A, also write
// tanhf(A) to tout[arow][kt+koff..] — fuses the out[0:384] write of the GAT
// branch into GEMM4 (each A element staged exactly once).
template<bool HAS_BIAS>
__global__ __launch_bounds__(256) void gemm64(const void* __restrict__ A,
    const int* __restrict__ aflag, const __bf16* __restrict__ Bt,
    const __bf16* __restrict__ bias,
    __bf16* __restrict__ C1, int n1, int ldc1,
    __bf16* __restrict__ C2, int ldc2,
    float* __restrict__ tout,
    int M, int K) {
  __shared__ __bf16 Al[64][40];
  __shared__ __bf16 Bl[128][40];
  int a32 = *aflag;
  int tid = threadIdx.x;
  int w = tid >> 6, lane = tid & 63;
  int quad = lane >> 4, r = lane & 15;
  int row0 = blockIdx.x * 64, col0 = blockIdx.y * 128;
  f32_4 acc[4][2] = {};
  int srow = tid >> 2;
  int koff = (tid & 3) * 8;
  int brow = tid >> 1;          // 0..127
  int bko  = (tid & 1) * 16;    // 0 or 16
  for (int kt = 0; kt < K; kt += 32) {
    int arow = row0 + srow;
    float va[8];
    if (a32) {
      float4 a0 = {0.f, 0.f, 0.f, 0.f}, a1 = {0.f, 0.f, 0.f, 0.f};
      if (arow < M) {
        const float* ap = (const float*)A + (size_t)arow * K + kt + koff;
        a0 = *(const float4*)ap;
        a1 = *(const float4*)(ap + 4);
      }
      bf16_8 t;
      t[0] = (__bf16)a0.x; t[1] = (__bf16)a0.y; t[2] = (__bf16)a0.z; t[3] = (__bf16)a0.w;
      t[4] = (__bf16)a1.x; t[5] = (__bf16)a1.y; t[6] = (__bf16)a1.z; t[7] = (__bf16)a1.w;
      *(bf16_8*)(&Al[srow][koff]) = t;
      va[0] = a0.x; va[1] = a0.y; va[2] = a0.z; va[3] = a0.w;
      va[4] = a1.x; va[5] = a1.y; va[6] = a1.z; va[7] = a1.w;
    } else {
      float4 av = {0.f, 0.f, 0.f, 0.f};
      if (arow < M) av = *(const float4*)((const __bf16*)A + (size_t)arow * K + kt + koff);
      *(float4*)(&Al[srow][koff]) = av;
      if (tout) {
        const __bf16* bp8 = (const __bf16*)&av;
#pragma unroll
        for (int q = 0; q < 8; q++) va[q] = (float)bp8[q];
      }
    }
    if (tout && arow < M) {
      float4 o0 = {tanhf(va[0]), tanhf(va[1]), tanhf(va[2]), tanhf(va[3])};
      float4 o1 = {tanhf(va[4]), tanhf(va[5]), tanhf(va[6]), tanhf(va[7])};
      float* op = tout + (size_t)arow * ODIM + kt + koff;
      *(float4*)op = o0;
      *(float4*)(op + 4) = o1;
    }
    const __bf16* bp = Bt + (size_t)(col0 + brow) * K + kt + bko;
    *(float4*)(&Bl[brow][bko])     = *(const float4*)bp;
    *(float4*)(&Bl[brow][bko + 8]) = *(const float4*)(bp + 8);
    __syncthreads();
    bf16_8 bfrag0 = *(const bf16_8*)(&Bl[w * 16 + r][quad * 8]);
    bf16_8 bfrag1 = *(const bf16_8*)(&Bl[64 + w * 16 + r][quad * 8]);
#pragma unroll
    for (int mt = 0; mt < 4; mt++) {
      bf16_8 afrag = *(const bf16_8*)(&Al[mt * 16 + r][quad * 8]);
      acc[mt][0] = __builtin_amdgcn_mfma_f32_16x16x32_bf16(afrag, bfrag0, acc[mt][0], 0, 0, 0);
      acc[mt][1] = __builtin_amdgcn_mfma_f32_16x16x32_bf16(afrag, bfrag1, acc[mt][1], 0, 0, 0);
    }
    __syncthreads();
  }
  __bf16* Cp; int ldc; int cbase;
  if (col0 < n1) { Cp = C1; ldc = ldc1; cbase = col0; }
  else           { Cp = C2; ldc = ldc2; cbase = col0 - n1; }
  int cc0 = cbase + w * 16 + r;
  int cc1 = cbase + 64 + w * 16 + r;
  float bv0 = HAS_BIAS ? (float)bias[col0 + w * 16 + r] : 0.0f;
  float bv1 = HAS_BIAS ? (float)bias[col0 + 64 + w * 16 + r] : 0.0f;
#pragma unroll
  for (int mt = 0; mt < 4; mt++) {
#pragma unroll
    for (int rr = 0; rr < 4; rr++) {
      int crow = row0 + mt * 16 + quad * 4 + rr;
      if (crow < M) {
        Cp[(size_t)crow * ldc + cc0] = (__bf16)(acc[mt][0][rr] + bv0);
        Cp[(size_t)crow * ldc + cc1] = (__bf16)(acc[mt][1][rr] + bv1);
      }
    }
  }
}

// ---------- attention logits: wave per (node,head) ---------- (R12 verbatim)
__global__ void k_alar_w(const __bf16* __restrict__ xwb, const __bf16* __restrict__ as_,
                         const __bf16* __restrict__ ad_,
                         float* __restrict__ al, float* __restrict__ ar) {
  int p = blockIdx.x * 4 + (threadIdx.x >> 6);
  int lane = threadIdx.x & 63;
  if (p >= NN * NH) return;
  int i = p / NH, h = p - i * NH;
  float xv = (float)xwb[(size_t)i * GATD + h * OUTD + lane];
  float s1 = xv * (float)as_[h * OUTD + lane];
  float s2 = xv * (float)ad_[h * OUTD + lane];
  for (int off = 32; off; off >>= 1) { s1 += __shfl_xor(s1, off); s2 += __shfl_xor(s2, off); }
  if (lane == 0) { al[p] = s1; ar[p] = s2; }
}

// ---------- GAT: wave per node, single pass ---------- (R12 inner loop; no out write)
__global__ __launch_bounds__(256) void k_gat2(const __bf16* __restrict__ xwb,
    const float* __restrict__ al, const float* __restrict__ ar,
    const int* __restrict__ rowstart, const int* __restrict__ csr_src,
    const __bf16* __restrict__ bgat,
    __bf16* __restrict__ h1b) {
  int wv = threadIdx.x >> 6, lane = threadIdx.x & 63;
  int i = blockIdx.x * 4 + wv;           // NN % 4 == 0
  __shared__ int   src_sh[4][64];
  __shared__ float ex_sh[4][64][NH];
  __shared__ int   mc_sh[4];
  int e0 = rowstart[i], e1 = rowstart[i + 1];
  if (lane == 0) mc_sh[wv] = (e1 - e0 + 63) >> 6;
  float arv[NH], exs[NH], acc[NH], denp[NH];
#pragma unroll
  for (int h = 0; h < NH; h++) arv[h] = ar[i * NH + h];
#pragma unroll
  for (int h = 0; h < NH; h++) {
    float e = lrelu(al[i * NH + h] + arv[h], 0.2f);
    exs[h] = __expf(e);                  // self-loop weight
    acc[h] = exs[h] * (float)xwb[(size_t)i * GATD + h * OUTD + lane];
    denp[h] = 0.f;
  }
  __syncthreads();
  int mch = max(max(mc_sh[0], mc_sh[1]), max(mc_sh[2], mc_sh[3]));
  for (int c = 0; c < mch; c++) {
    if (c) __syncthreads();
    int base = e0 + c * 64;
    int cnt = e1 - base; cnt = cnt < 0 ? 0 : (cnt > 64 ? 64 : cnt);
    if (lane < cnt) {
      int s = csr_src[base + lane];
      src_sh[wv][lane] = s;
#pragma unroll
      for (int h = 0; h < NH; h++) {
        float ex = __expf(lrelu(al[s * NH + h] + arv[h], 0.2f));
        ex_sh[wv][lane][h] = ex;
        denp[h] += ex;
      }
    }
    __syncthreads();
    int j = 0;
    for (; j + 2 <= cnt; j += 2) {
      int s0 = src_sh[wv][j], s1 = src_sh[wv][j + 1];
      const __bf16* r0 = xwb + (size_t)s0 * GATD + lane;
      const __bf16* r1 = xwb + (size_t)s1 * GATD + lane;
      float x0[NH], x1[NH];
#pragma unroll
      for (int h = 0; h < NH; h++) { x0[h] = (float)r0[h * OUTD]; x1[h] = (float)r1[h * OUTD]; }
#pragma unroll
      for (int h = 0; h < NH; h++)
        acc[h] += ex_sh[wv][j][h] * x0[h] + ex_sh[wv][j + 1][h] * x1[h];
    }
    if (j < cnt) {
      int s0 = src_sh[wv][j];
      const __bf16* r0 = xwb + (size_t)s0 * GATD + lane;
#pragma unroll
      for (int h = 0; h < NH; h++) acc[h] += ex_sh[wv][j][h] * (float)r0[h * OUTD];
    }
  }
#pragma unroll
  for (int h = 0; h < NH; h++) {
    float d = denp[h];
    for (int off = 32; off; off >>= 1) d += __shfl_xor(d, off);
    d += exs[h];
    float v = acc[h] / d + (float)bgat[h * OUTD + lane];
    v = lrelu(v, 0.01f);
    h1b[(size_t)i * GATD + h * OUTD + lane] = (__bf16)v;  // out[0:384] written by GEMM4 (tanh-fused)
  }
}

// ---------- fused GCN0+GCN1+ARMA: wave per node, single pass ---------- (R12 verbatim)
__global__ __launch_bounds__(256) void k_gcnarma2(const __bf16* __restrict__ xwgb,
    const __bf16* __restrict__ trb, const int* __restrict__ rowstart,
    const int* __restrict__ csr_src, const float* __restrict__ csr_w,
    const float* __restrict__ dgcn, const float* __restrict__ darma,
    const __bf16* __restrict__ b0, const __bf16* __restrict__ b1,
    const __bf16* __restrict__ ba, float* __restrict__ out) {
  int wv = threadIdx.x >> 6, lane = threadIdx.x & 63;
  int i = blockIdx.x * 4 + wv;
  __shared__ int   src_sh[4][64];
  __shared__ float wg_sh[4][64], wa_sh[4][64];
  __shared__ int   mc_sh[4];
  int e0 = rowstart[i], e1 = rowstart[i + 1];
  if (lane == 0) mc_sh[wv] = (e1 - e0 + 63) >> 6;
  __syncthreads();
  int mch = max(max(mc_sh[0], mc_sh[1]), max(mc_sh[2], mc_sh[3]));
  float g0 = 0.f, g1 = 0.f, aa = 0.f;
  for (int c = 0; c < mch; c++) {
    if (c) __syncthreads();
    int base = e0 + c * 64;
    int cnt = e1 - base; cnt = cnt < 0 ? 0 : (cnt > 64 ? 64 : cnt);
    if (lane < cnt) {
      int eidx = base + lane;
      int s = csr_src[eidx];
      float wvv = csr_w[eidx];
      src_sh[wv][lane] = s;
      wg_sh[wv][lane] = dgcn[s] * wvv;
      wa_sh[wv][lane] = darma[s] * wvv;
    }
    __syncthreads();
    int j = 0;
    for (; j + 2 <= cnt; j += 2) {
      int s0 = src_sh[wv][j], s1 = src_sh[wv][j + 1];
      float wg0 = wg_sh[wv][j], wg1 = wg_sh[wv][j + 1];
      float wa0 = wa_sh[wv][j], wa1 = wa_sh[wv][j + 1];
      const __bf16* p0 = xwgb + (size_t)s0 * 128;
      const __bf16* p1 = xwgb + (size_t)s1 * 128;
      const __bf16* q0 = trb + (size_t)s0 * 128;
      const __bf16* q1 = trb + (size_t)s1 * 128;
      g0 += wg0 * (float)p0[lane] + wg1 * (float)p1[lane];
      g1 += wg0 * (float)p0[lane + 64] + wg1 * (float)p1[lane + 64];
      aa += wa0 * (float)q0[lane] + wa1 * (float)q1[lane];
    }
    if (j < cnt) {
      int s0 = src_sh[wv][j];
      float wg0 = wg_sh[wv][j], wa0 = wa_sh[wv][j];
      const __bf16* p0 = xwgb + (size_t)s0 * 128;
      const __bf16* q0 = trb + (size_t)s0 * 128;
      g0 += wg0 * (float)p0[lane];
      g1 += wg0 * (float)p0[lane + 64];
      aa += wa0 * (float)q0[lane];
    }
  }
  float di = dgcn[i];
  float v0 = lrelu(di * g0 + di * di * (float)xwgb[(size_t)i * 128 + lane] + (float)b0[lane], 0.01f);
  float v1 = lrelu(di * g1 + di * di * (float)xwgb[(size_t)i * 128 + 64 + lane] + (float)b1[lane], 0.01f);
  out[(size_t)i * ODIM + 384 + lane] = tanhf(v0);
  out[(size_t)i * ODIM + 448 + lane] = tanhf(v1);
  float va = darma[i] * aa + (float)trb[(size_t)i * 128 + 64 + lane] + (float)ba[lane];
  va = fmaxf(va, 0.f);
  out[(size_t)i * ODIM + 512 + lane] = tanhf(va);
}

extern "C" void kernel_launch(void* const* d_in, const int* in_sizes, int n_in,
                              void* d_out, int out_size, void* d_ws, size_t ws_size,
                              hipStream_t stream) {
  const int* ei = (const int*)d_in[1];
  float* out = (float*)d_out;

  char* ws = (char*)d_ws;
  size_t off = 0;
  auto alloc = [&](size_t bytes) -> void* {
    void* p = ws + off;
    off += (bytes + 255) & ~(size_t)255;
    return p;
  };
  int*    flags    = (int*)alloc(32 * 4);
  int*    deg      = (int*)alloc((size_t)3 * NN * 4);
  int*    cursor   = deg + NN;
  float*  wdeg     = (float*)(deg + 2 * NN);
  int*    rowstart = (int*)alloc((size_t)(NN + 1) * 4);
  int*    csr_src  = (int*)alloc((size_t)EE * 4);
  float*  csr_w    = (float*)alloc((size_t)EE * 4);
  float*  dgcn     = (float*)alloc((size_t)NN * 4);
  float*  darma    = (float*)alloc((size_t)NN * 4);
  float*  al       = (float*)alloc((size_t)NN * NH * 4);
  float*  ar       = (float*)alloc((size_t)NN * NH * 4);
  __bf16* bpb   = (__bf16*)alloc(256 * 2);
  __bf16* asb   = (__bf16*)alloc(384 * 2);
  __bf16* adb   = (__bf16*)alloc(384 * 2);
  __bf16* bgatb = (__bf16*)alloc(384 * 2);
  __bf16* bg0b  = (__bf16*)alloc(64 * 2);
  __bf16* bg1b  = (__bf16*)alloc(64 * 2);
  __bf16* bab   = (__bf16*)alloc(64 * 2);
  __bf16* Wp_t    = (__bf16*)alloc(256 * 256 * 2);
  // Wgat_t and Wg01_t contiguous -> single fused GEMM (N=512)
  __bf16* Wcat_t  = (__bf16*)alloc((size_t)(384 + 128) * 256 * 2);
  __bf16* Wgat_t  = Wcat_t;
  __bf16* Wg01_t  = Wcat_t + (size_t)384 * 256;
  __bf16* Warma_t = (__bf16*)alloc(128 * 384 * 2);
  char* regA = (char*)alloc((size_t)NN * GATD * 2);
  __bf16* h   = (__bf16*)regA;   // dead after fused gemm
  __bf16* h1b = (__bf16*)regA;
  char* regB = (char*)alloc((size_t)NN * GATD * 2);
  __bf16* xwb = (__bf16*)regB;   // dead after k_gat2
  __bf16* trb = (__bf16*)regB;
  __bf16* xwgb = (__bf16*)alloc((size_t)NN * 128 * 2);
  (void)ws_size; (void)in_sizes; (void)n_in; (void)out_size;

  hipMemsetAsync(ws, 0, 256 + (size_t)3 * NN * 4, stream);

  dim3 tb(256);
  // fused probes
  ProbeArgs pa;
  const int pidx[15] = {0, 2, 3, 4, 5, 6, 7, 8, 9, 10, 11, 12, 13, 14, 15};
  const int pcnt[15] = {NN * 256, EE, 256 * 256, 256, 256 * 384, NH * OUTD, NH * OUTD,
                        NH * OUTD, 256 * 64, 64, 256 * 64, 64, GATD * OUTD, GATD * OUTD, 64};
  for (int k = 0; k < 15; k++) { pa.ptr[k] = d_in[pidx[k]]; pa.cnt[k] = pcnt[k]; pa.flagidx[k] = pidx[k]; }
  pa.ei = ei;
  k_probe_all<<<dim3(16), tb, 0, stream>>>(pa, flags);

  // merged conversions: biases/attn vectors + the 6 weight matrices
  CvtArgs ca;
  TArgs ta;
  int cvtblk = 0, tblk = 0;
  {
    struct { int idx; __bf16* out; int n; } cv[7] = {
      {4, bpb, 256}, {6, asb, 384}, {7, adb, 384}, {8, bgatb, 384},
      {10, bg0b, 64}, {12, bg1b, 64}, {15, bab, 64},
    };
    for (int k = 0; k < 7; k++) {
      ca.s[k].in = d_in[cv[k].idx]; ca.s[k].out = cv[k].out; ca.s[k].n = cv[k].n;
      ca.s[k].flagidx = cv[k].idx; ca.s[k].blk0 = cvtblk;
      cvtblk += (cv[k].n + 255) / 256;
    }
    struct { int idx; __bf16* out; int R; int C; } tv[6] = {
      {3,  Wp_t,             256, 256},
      {5,  Wgat_t,           256, 384},
      {9,  Wg01_t,           256, 64},
      {11, Wg01_t + 64 * 256, 256, 64},
      {13, Warma_t,          384, 64},
      {14, Warma_t + 64 * 384, 384, 64},
    };
    for (int k = 0; k < 6; k++) {
      ta.s[k].in = d_in[tv[k].idx]; ta.s[k].out = tv[k].out;
      ta.s[k].R = tv[k].R; ta.s[k].C = tv[k].C;
      ta.s[k].flagidx = tv[k].idx; ta.s[k].blk0 = tblk;
      tblk += ((tv[k].R + 31) / 32) * ((tv[k].C + 31) / 32);
    }
    k_cvt_merged<<<dim3(cvtblk + tblk), tb, 0, stream>>>(ca, cvtblk, ta, flags);
  }

  // CSR by dst + degree norms (dinv folded into scan)
  k_count<<<dim3((EE + 255) / 256), tb, 0, stream>>>(ei, d_in[2], flags, deg, wdeg);
  k_scan<<<dim3(1), tb, 0, stream>>>(deg, wdeg, rowstart, dgcn, darma);
  k_fill<<<dim3((EE + 255) / 256), tb, 0, stream>>>(ei, d_in[2], flags, rowstart, cursor, csr_src, csr_w);

  const int MB64 = (NN + 63) / 64;  // 313
  // h = x @ Wp + bp   (N=256 -> 2 col-128 blocks)
  gemm64<true ><<<dim3(MB64, 2), tb, 0, stream>>>(d_in[0], &flags[0], Wp_t, bpb,
                                                  h, 256, 256, nullptr, 0, nullptr, NN, 256);
  // fused: xwb = h @ Wgat (cols 0..383), xwgb = h @ Wgcn01 (cols 384..511); N=512 -> 4 blocks
  gemm64<false><<<dim3(MB64, 4), tb, 0, stream>>>(h, &flags[30], Wcat_t, nullptr,
                                                  xwb, 384, 384, xwgb, 128, nullptr, NN, 256);
  k_alar_w<<<dim3((NN * NH + 3) / 4), tb, 0, stream>>>(xwb, asb, adb, al, ar);
  // h dead; h1b overwrites region A
  k_gat2<<<dim3(NN / 4), tb, 0, stream>>>(xwb, al, ar, rowstart, csr_src, bgatb, h1b);
  // xwb dead; trb overwrites region B. N=128 -> 1 block; grid.y==1 so the
  // tanh-fused A-staging writes out[0:384] exactly once per element.
  gemm64<false><<<dim3(MB64, 1), tb, 0, stream>>>(h1b, &flags[30], Warma_t, nullptr,
                                                  trb, 128, 128, nullptr, 0, out, NN, 384);
  k_gcnarma2<<<dim3(NN / 4), tb, 0, stream>>>(xwgb, trb, rowstart, csr_src, csr_w,
                                              dgcn, darma, bg0b, bg1b, bab, out);
}

// Round 6
// 296.189 us; speedup vs baseline: 1.2015x; 1.2015x over previous
//
#include <hip/hip_runtime.h>

// R18: scan fixed. R17's top-5 revealed k_scan = ~57us: a ONE-BLOCK kernel with
// per-thread serial uncoalesced 79-element runs (hidden at ~40-50us in all
// earlier rounds). Replaced with 2 parallel coalesced kernels (79 blocks each):
// k_scan1 block-sums, k_scan2 base-reduce + in-block shuffle scan + dinv tail.
// Everything else reverted VERBATIM to R16 (329.5us measured): R12 gathers,
// 64x128 GEMM tile, fused dual-output GEMM. k_cvt_merged kept. 12 launches.

#define NN 20000
#define EE 320000
#define GATD 384
#define NH 6
#define OUTD 64
#define ODIM 576

typedef __bf16 bf16_8 __attribute__((ext_vector_type(8)));
typedef float f32_4 __attribute__((ext_vector_type(4)));

__device__ __forceinline__ float lrelu(float x, float s) { return x > 0.f ? x : s * x; }

__device__ __forceinline__ float loadf(const void* p, size_t i, int f32) {
  return f32 ? ((const float*)p)[i] : (float)((const __bf16*)p)[i];
}

// ---------- fused dtype probes ----------
struct ProbeArgs {
  const void* ptr[15];
  int cnt[15];
  int flagidx[15];
  const int* ei;
};
__global__ void k_probe_all(ProbeArgs a, int* __restrict__ flags) {
  __shared__ int cnt;
  if (threadIdx.x == 0) cnt = 0;
  __syncthreads();
  int b = blockIdx.x;
  if (b < 15) {
    const unsigned short* u = (const unsigned short*)a.ptr[b];
    int m = a.cnt[b] < 2048 ? a.cnt[b] : 2048;
    int c = 0;
    for (int i = threadIdx.x; i < m; i += 256) {
      float v = __uint_as_float(((unsigned int)u[i]) << 16);
      if (!(fabsf(v) < 1e4f)) c++;
    }
    if (c) atomicAdd(&cnt, c);
    __syncthreads();
    if (threadIdx.x == 0) flags[a.flagidx[b]] = (cnt > m / 16) ? 1 : 0;
  } else {
    int c = 0;
    for (int i = threadIdx.x; i < 1024; i += 256)
      if (a.ei[2 * i + 1] != 0) c++;
    if (c) atomicAdd(&cnt, c);
    __syncthreads();
    if (threadIdx.x == 0) flags[16] = (cnt <= 2) ? 1 : 0;
  }
}

// ---------- merged small conversions + weight cvt/transpose ----------
struct CvtSeg { const void* in; __bf16* out; int n; int flagidx; int blk0; };
struct CvtArgs { CvtSeg s[7]; };
struct TSeg { const void* in; __bf16* out; int R; int C; int flagidx; int blk0; };
struct TArgs { TSeg s[6]; };
__global__ void k_cvt_merged(CvtArgs ca, int ncvtblk, TArgs ta, const int* __restrict__ flags) {
  if ((int)blockIdx.x < ncvtblk) {
    int b = blockIdx.x;
    int k = 0;
    while (k + 1 < 7 && ca.s[k + 1].blk0 <= b) k++;
    const CvtSeg sg = ca.s[k];
    int i = (b - sg.blk0) * 256 + threadIdx.x;
    if (i >= sg.n) return;
    sg.out[i] = flags[sg.flagidx] ? (__bf16)((const float*)sg.in)[i] : ((const __bf16*)sg.in)[i];
    return;
  }
  __shared__ float t[32][33];
  int b = blockIdx.x - ncvtblk;
  int k = 0;
  while (k + 1 < 6 && ta.s[k + 1].blk0 <= b) k++;
  const TSeg sg = ta.s[k];
  int f32 = flags[sg.flagidx];
  int tpx = (sg.C + 31) >> 5;
  int lt = b - sg.blk0;
  int c0 = (lt % tpx) * 32, r0 = (lt / tpx) * 32;
  int tid = threadIdx.x;
  for (int idx = tid; idx < 1024; idx += 256) {
    int r = idx >> 5, c = idx & 31;
    if (r0 + r < sg.R && c0 + c < sg.C)
      t[r][c] = loadf(sg.in, (size_t)(r0 + r) * sg.C + (c0 + c), f32);
  }
  __syncthreads();
  for (int idx = tid; idx < 1024; idx += 256) {
    int r = idx >> 5, c = idx & 31;
    if (c0 + r < sg.C && r0 + c < sg.R)
      sg.out[(size_t)(c0 + r) * sg.R + (r0 + c)] = (__bf16)t[c][r];
  }
}

// ---------- CSR build ----------
__global__ void k_count(const int* __restrict__ ei, const void* __restrict__ ew,
                        const int* __restrict__ flags,
                        int* __restrict__ deg, float* __restrict__ wdeg) {
  int e = blockIdx.x * 256 + threadIdx.x;
  if (e >= EE) return;
  int sh = flags[16];
  int d = ei[(size_t)(EE + e) << sh];
  atomicAdd(&deg[d], 1);
  atomicAdd(&wdeg[d], loadf(ew, e, flags[2]));
}

// parallel coalesced scan, phase 1: per-block sums of deg
__global__ __launch_bounds__(256) void k_scan1(const int* __restrict__ deg,
                                               int* __restrict__ bsum) {
  int i = blockIdx.x * 256 + threadIdx.x;
  int v = (i < NN) ? deg[i] : 0;
  for (int off = 32; off; off >>= 1) v += __shfl_xor(v, off);
  __shared__ int ws[4];
  if ((threadIdx.x & 63) == 0) ws[threadIdx.x >> 6] = v;
  __syncthreads();
  if (threadIdx.x == 0) bsum[blockIdx.x] = ws[0] + ws[1] + ws[2] + ws[3];
}

// phase 2: base = sum(bsum[0..b-1]); in-block shuffle scan; rowstart write;
// dinv elementwise tail (all coalesced, 79-way block parallel)
__global__ __launch_bounds__(256) void k_scan2(const int* __restrict__ deg,
    const int* __restrict__ bsum, const float* __restrict__ wdeg,
    int* __restrict__ rowstart, float* __restrict__ dg, float* __restrict__ da) {
  int b = blockIdx.x;
  int tid = threadIdx.x;
  int lane = tid & 63, wv = tid >> 6;
  int i = b * 256 + tid;
  __shared__ int red[4];
  __shared__ int wsum2[4];
  __shared__ int sbase;
  // base = sum of earlier block sums (b <= 78 < 256, one pass)
  {
    int v = (tid < b) ? bsum[tid] : 0;
    for (int off = 32; off; off >>= 1) v += __shfl_xor(v, off);
    if (lane == 0) red[wv] = v;
    __syncthreads();
    if (tid == 0) sbase = red[0] + red[1] + red[2] + red[3];
    __syncthreads();
  }
  int v = (i < NN) ? deg[i] : 0;
  int run = v;
  for (int off = 1; off < 64; off <<= 1) {
    int u = __shfl_up(run, off);
    if (lane >= off) run += u;
  }
  if (lane == 63) wsum2[wv] = run;
  __syncthreads();
  int wb = 0;
#pragma unroll
  for (int w = 0; w < 4; w++) { int x = wsum2[w]; if (w < wv) wb += x; }
  int excl = sbase + wb + run - v;
  if (i < NN) rowstart[i] = excl;
  if (i == NN - 1) rowstart[NN] = excl + v;
  if (i < NN) {
    float w = wdeg[i];
    dg[i] = rsqrtf(w + 1.0f);
    da[i] = w > 0.f ? rsqrtf(w) : 0.f;
  }
}

__global__ void k_fill(const int* __restrict__ ei, const void* __restrict__ ew,
                       const int* __restrict__ flags, const int* __restrict__ rowstart,
                       int* __restrict__ cursor,
                       int* __restrict__ csr_src, float* __restrict__ csr_w) {
  int e = blockIdx.x * 256 + threadIdx.x;
  if (e >= EE) return;
  int sh = flags[16];
  int d = ei[(size_t)(EE + e) << sh];
  int s = ei[(size_t)e << sh];
  int pos = rowstart[d] + atomicAdd(&cursor[d], 1);
  csr_src[pos] = s;
  csr_w[pos] = loadf(ew, e, flags[2]);
}

// ---------- MFMA GEMM: C[M][N] = A[M][K] * Bt[N][K]^T (+bias), bf16 out ----------
// 64x128 block tile (acc[4][2], 8 MFMA/K-step). Dual-output epilogue
// (col0 < n1 -> C1 else C2, col rebased); n1 % 128 == 0.  (R16 verbatim)
template<bool HAS_BIAS>
__global__ __launch_bounds__(256) void gemm64(const void* __restrict__ A,
    const int* __restrict__ aflag, const __bf16* __restrict__ Bt,
    const __bf16* __restrict__ bias,
    __bf16* __restrict__ C1, int n1, int ldc1,
    __bf16* __restrict__ C2, int ldc2,
    int M, int K) {
  __shared__ __bf16 Al[64][40];
  __shared__ __bf16 Bl[128][40];
  int a32 = *aflag;
  int tid = threadIdx.x;
  int w = tid >> 6, lane = tid & 63;
  int quad = lane >> 4, r = lane & 15;
  int row0 = blockIdx.x * 64, col0 = blockIdx.y * 128;
  f32_4 acc[4][2] = {};
  int srow = tid >> 2;
  int koff = (tid & 3) * 8;
  int brow = tid >> 1;          // 0..127
  int bko  = (tid & 1) * 16;    // 0 or 16
  for (int kt = 0; kt < K; kt += 32) {
    int arow = row0 + srow;
    if (a32) {
      float4 a0 = {0.f, 0.f, 0.f, 0.f}, a1 = {0.f, 0.f, 0.f, 0.f};
      if (arow < M) {
        const float* ap = (const float*)A + (size_t)arow * K + kt + koff;
        a0 = *(const float4*)ap;
        a1 = *(const float4*)(ap + 4);
      }
      bf16_8 t;
      t[0] = (__bf16)a0.x; t[1] = (__bf16)a0.y; t[2] = (__bf16)a0.z; t[3] = (__bf16)a0.w;
      t[4] = (__bf16)a1.x; t[5] = (__bf16)a1.y; t[6] = (__bf16)a1.z; t[7] = (__bf16)a1.w;
      *(bf16_8*)(&Al[srow][koff]) = t;
    } else {
      float4 av = {0.f, 0.f, 0.f, 0.f};
      if (arow < M) av = *(const float4*)((const __bf16*)A + (size_t)arow * K + kt + koff);
      *(float4*)(&Al[srow][koff]) = av;
    }
    const __bf16* bp = Bt + (size_t)(col0 + brow) * K + kt + bko;
    *(float4*)(&Bl[brow][bko])     = *(const float4*)bp;
    *(float4*)(&Bl[brow][bko + 8]) = *(const float4*)(bp + 8);
    __syncthreads();
    bf16_8 bfrag0 = *(const bf16_8*)(&Bl[w * 16 + r][quad * 8]);
    bf16_8 bfrag1 = *(const bf16_8*)(&Bl[64 + w * 16 + r][quad * 8]);
#pragma unroll
    for (int mt = 0; mt < 4; mt++) {
      bf16_8 afrag = *(const bf16_8*)(&Al[mt * 16 + r][quad * 8]);
      acc[mt][0] = __builtin_amdgcn_mfma_f32_16x16x32_bf16(afrag, bfrag0, acc[mt][0], 0, 0, 0);
      acc[mt][1] = __builtin_amdgcn_mfma_f32_16x16x32_bf16(afrag, bfrag1, acc[mt][1], 0, 0, 0);
    }
    __syncthreads();
  }
  __bf16* Cp; int ldc; int cbase;
  if (col0 < n1) { Cp = C1; ldc = ldc1; cbase = col0; }
  else           { Cp = C2; ldc = ldc2; cbase = col0 - n1; }
  int cc0 = cbase + w * 16 + r;
  int cc1 = cbase + 64 + w * 16 + r;
  float bv0 = HAS_BIAS ? (float)bias[col0 + w * 16 + r] : 0.0f;
  float bv1 = HAS_BIAS ? (float)bias[col0 + 64 + w * 16 + r] : 0.0f;
#pragma unroll
  for (int mt = 0; mt < 4; mt++) {
#pragma unroll
    for (int rr = 0; rr < 4; rr++) {
      int crow = row0 + mt * 16 + quad * 4 + rr;
      if (crow < M) {
        Cp[(size_t)crow * ldc + cc0] = (__bf16)(acc[mt][0][rr] + bv0);
        Cp[(size_t)crow * ldc + cc1] = (__bf16)(acc[mt][1][rr] + bv1);
      }
    }
  }
}

// ---------- attention logits: wave per (node,head) ---------- (R12 verbatim)
__global__ void k_alar_w(const __bf16* __restrict__ xwb, const __bf16* __restrict__ as_,
                         const __bf16* __restrict__ ad_,
                         float* __restrict__ al, float* __restrict__ ar) {
  int p = blockIdx.x * 4 + (threadIdx.x >> 6);
  int lane = threadIdx.x & 63;
  if (p >= NN * NH) return;
  int i = p / NH, h = p - i * NH;
  float xv = (float)xwb[(size_t)i * GATD + h * OUTD + lane];
  float s1 = xv * (float)as_[h * OUTD + lane];
  float s2 = xv * (float)ad_[h * OUTD + lane];
  for (int off = 32; off; off >>= 1) { s1 += __shfl_xor(s1, off); s2 += __shfl_xor(s2, off); }
  if (lane == 0) { al[p] = s1; ar[p] = s2; }
}

// ---------- GAT: wave per node, single pass ---------- (R12 verbatim)
__global__ __launch_bounds__(256) void k_gat2(const __bf16* __restrict__ xwb,
    const float* __restrict__ al, const float* __restrict__ ar,
    const int* __restrict__ rowstart, const int* __restrict__ csr_src,
    const __bf16* __restrict__ bgat,
    __bf16* __restrict__ h1b, float* __restrict__ out) {
  int wv = threadIdx.x >> 6, lane = threadIdx.x & 63;
  int i = blockIdx.x * 4 + wv;           // NN % 4 == 0
  __shared__ int   src_sh[4][64];
  __shared__ float ex_sh[4][64][NH];
  __shared__ int   mc_sh[4];
  int e0 = rowstart[i], e1 = rowstart[i + 1];
  if (lane == 0) mc_sh[wv] = (e1 - e0 + 63) >> 6;
  float arv[NH], exs[NH], acc[NH], denp[NH];
#pragma unroll
  for (int h = 0; h < NH; h++) arv[h] = ar[i * NH + h];
#pragma unroll
  for (int h = 0; h < NH; h++) {
    float e = lrelu(al[i * NH + h] + arv[h], 0.2f);
    exs[h] = __expf(e);                  // self-loop weight
    acc[h] = exs[h] * (float)xwb[(size_t)i * GATD + h * OUTD + lane];
    denp[h] = 0.f;
  }
  __syncthreads();
  int mch = max(max(mc_sh[0], mc_sh[1]), max(mc_sh[2], mc_sh[3]));
  for (int c = 0; c < mch; c++) {
    if (c) __syncthreads();
    int base = e0 + c * 64;
    int cnt = e1 - base; cnt = cnt < 0 ? 0 : (cnt > 64 ? 64 : cnt);
    if (lane < cnt) {
      int s = csr_src[base + lane];
      src_sh[wv][lane] = s;
#pragma unroll
      for (int h = 0; h < NH; h++) {
        float ex = __expf(lrelu(al[s * NH + h] + arv[h], 0.2f));
        ex_sh[wv][lane][h] = ex;
        denp[h] += ex;
      }
    }
    __syncthreads();
    int j = 0;
    for (; j + 2 <= cnt; j += 2) {
      int s0 = src_sh[wv][j], s1 = src_sh[wv][j + 1];
      const __bf16* r0 = xwb + (size_t)s0 * GATD + lane;
      const __bf16* r1 = xwb + (size_t)s1 * GATD + lane;
      float x0[NH], x1[NH];
#pragma unroll
      for (int h = 0; h < NH; h++) { x0[h] = (float)r0[h * OUTD]; x1[h] = (float)r1[h * OUTD]; }
#pragma unroll
      for (int h = 0; h < NH; h++)
        acc[h] += ex_sh[wv][j][h] * x0[h] + ex_sh[wv][j + 1][h] * x1[h];
    }
    if (j < cnt) {
      int s0 = src_sh[wv][j];
      const __bf16* r0 = xwb + (size_t)s0 * GATD + lane;
#pragma unroll
      for (int h = 0; h < NH; h++) acc[h] += ex_sh[wv][j][h] * (float)r0[h * OUTD];
    }
  }
#pragma unroll
  for (int h = 0; h < NH; h++) {
    float d = denp[h];
    for (int off = 32; off; off >>= 1) d += __shfl_xor(d, off);
    d += exs[h];
    float v = acc[h] / d + (float)bgat[h * OUTD + lane];
    v = lrelu(v, 0.01f);
    h1b[(size_t)i * GATD + h * OUTD + lane] = (__bf16)v;
    out[(size_t)i * ODIM + h * OUTD + lane] = tanhf(v);
  }
}

// ---------- fused GCN0+GCN1+ARMA: wave per node, single pass ---------- (R12 verbatim)
__global__ __launch_bounds__(256) void k_gcnarma2(const __bf16* __restrict__ xwgb,
    const __bf16* __restrict__ trb, const int* __restrict__ rowstart,
    const int* __restrict__ csr_src, const float* __restrict__ csr_w,
    const float* __restrict__ dgcn, const float* __restrict__ darma,
    const __bf16* __restrict__ b0, const __bf16* __restrict__ b1,
    const __bf16* __restrict__ ba, float* __restrict__ out) {
  int wv = threadIdx.x >> 6, lane = threadIdx.x & 63;
  int i = blockIdx.x * 4 + wv;
  __shared__ int   src_sh[4][64];
  __shared__ float wg_sh[4][64], wa_sh[4][64];
  __shared__ int   mc_sh[4];
  int e0 = rowstart[i], e1 = rowstart[i + 1];
  if (lane == 0) mc_sh[wv] = (e1 - e0 + 63) >> 6;
  __syncthreads();
  int mch = max(max(mc_sh[0], mc_sh[1]), max(mc_sh[2], mc_sh[3]));
  float g0 = 0.f, g1 = 0.f, aa = 0.f;
  for (int c = 0; c < mch; c++) {
    if (c) __syncthreads();
    int base = e0 + c * 64;
    int cnt = e1 - base; cnt = cnt < 0 ? 0 : (cnt > 64 ? 64 : cnt);
    if (lane < cnt) {
      int eidx = base + lane;
      int s = csr_src[eidx];
      float wvv = csr_w[eidx];
      src_sh[wv][lane] = s;
      wg_sh[wv][lane] = dgcn[s] * wvv;
      wa_sh[wv][lane] = darma[s] * wvv;
    }
    __syncthreads();
    int j = 0;
    for (; j + 2 <= cnt; j += 2) {
      int s0 = src_sh[wv][j], s1 = src_sh[wv][j + 1];
      float wg0 = wg_sh[wv][j], wg1 = wg_sh[wv][j + 1];
      float wa0 = wa_sh[wv][j], wa1 = wa_sh[wv][j + 1];
      const __bf16* p0 = xwgb + (size_t)s0 * 128;
      const __bf16* p1 = xwgb + (size_t)s1 * 128;
      const __bf16* q0 = trb + (size_t)s0 * 128;
      const __bf16* q1 = trb + (size_t)s1 * 128;
      g0 += wg0 * (float)p0[lane] + wg1 * (float)p1[lane];
      g1 += wg0 * (float)p0[lane + 64] + wg1 * (float)p1[lane + 64];
      aa += wa0 * (float)q0[lane] + wa1 * (float)q1[lane];
    }
    if (j < cnt) {
      int s0 = src_sh[wv][j];
      float wg0 = wg_sh[wv][j], wa0 = wa_sh[wv][j];
      const __bf16* p0 = xwgb + (size_t)s0 * 128;
      const __bf16* q0 = trb + (size_t)s0 * 128;
      g0 += wg0 * (float)p0[lane];
      g1 += wg0 * (float)p0[lane + 64];
      aa += wa0 * (float)q0[lane];
    }
  }
  float di = dgcn[i];
  float v0 = lrelu(di * g0 + di * di * (float)xwgb[(size_t)i * 128 + lane] + (float)b0[lane], 0.01f);
  float v1 = lrelu(di * g1 + di * di * (float)xwgb[(size_t)i * 128 + 64 + lane] + (float)b1[lane], 0.01f);
  out[(size_t)i * ODIM + 384 + lane] = tanhf(v0);
  out[(size_t)i * ODIM + 448 + lane] = tanhf(v1);
  float va = darma[i] * aa + (float)trb[(size_t)i * 128 + 64 + lane] + (float)ba[lane];
  va = fmaxf(va, 0.f);
  out[(size_t)i * ODIM + 512 + lane] = tanhf(va);
}

extern "C" void kernel_launch(void* const* d_in, const int* in_sizes, int n_in,
                              void* d_out, int out_size, void* d_ws, size_t ws_size,
                              hipStream_t stream) {
  const int* ei = (const int*)d_in[1];
  float* out = (float*)d_out;

  char* ws = (char*)d_ws;
  size_t off = 0;
  auto alloc = [&](size_t bytes) -> void* {
    void* p = ws + off;
    off += (bytes + 255) & ~(size_t)255;
    return p;
  };
  int*    flags    = (int*)alloc(32 * 4);
  int*    deg      = (int*)alloc((size_t)3 * NN * 4);
  int*    cursor   = deg + NN;
  float*  wdeg     = (float*)(deg + 2 * NN);
  int*    bsum     = (int*)alloc(128 * 4);
  int*    rowstart = (int*)alloc((size_t)(NN + 1) * 4);
  int*    csr_src  = (int*)alloc((size_t)EE * 4);
  float*  csr_w    = (float*)alloc((size_t)EE * 4);
  float*  dgcn     = (float*)alloc((size_t)NN * 4);
  float*  darma    = (float*)alloc((size_t)NN * 4);
  float*  al       = (float*)alloc((size_t)NN * NH * 4);
  float*  ar       = (float*)alloc((size_t)NN * NH * 4);
  __bf16* bpb   = (__bf16*)alloc(256 * 2);
  __bf16* asb   = (__bf16*)alloc(384 * 2);
  __bf16* adb   = (__bf16*)alloc(384 * 2);
  __bf16* bgatb = (__bf16*)alloc(384 * 2);
  __bf16* bg0b  = (__bf16*)alloc(64 * 2);
  __bf16* bg1b  = (__bf16*)alloc(64 * 2);
  __bf16* bab   = (__bf16*)alloc(64 * 2);
  __bf16* Wp_t    = (__bf16*)alloc(256 * 256 * 2);
  // Wgat_t and Wg01_t contiguous -> single fused GEMM (N=512)
  __bf16* Wcat_t  = (__bf16*)alloc((size_t)(384 + 128) * 256 * 2);
  __bf16* Wgat_t  = Wcat_t;
  __bf16* Wg01_t  = Wcat_t + (size_t)384 * 256;
  __bf16* Warma_t = (__bf16*)alloc(128 * 384 * 2);
  char* regA = (char*)alloc((size_t)NN * GATD * 2);
  __bf16* h   = (__bf16*)regA;   // dead after fused gemm
  __bf16* h1b = (__bf16*)regA;
  char* regB = (char*)alloc((size_t)NN * GATD * 2);
  __bf16* xwb = (__bf16*)regB;   // dead after k_gat2
  __bf16* trb = (__bf16*)regB;
  __bf16* xwgb = (__bf16*)alloc((size_t)NN * 128 * 2);
  (void)ws_size; (void)in_sizes; (void)n_in; (void)out_size;

  hipMemsetAsync(ws, 0, 256 + (size_t)3 * NN * 4, stream);

  dim3 tb(256);
  // fused probes
  ProbeArgs pa;
  const int pidx[15] = {0, 2, 3, 4, 5, 6, 7, 8, 9, 10, 11, 12, 13, 14, 15};
  const int pcnt[15] = {NN * 256, EE, 256 * 256, 256, 256 * 384, NH * OUTD, NH * OUTD,
                        NH * OUTD, 256 * 64, 64, 256 * 64, 64, GATD * OUTD, GATD * OUTD, 64};
  for (int k = 0; k < 15; k++) { pa.ptr[k] = d_in[pidx[k]]; pa.cnt[k] = pcnt[k]; pa.flagidx[k] = pidx[k]; }
  pa.ei = ei;
  k_probe_all<<<dim3(16), tb, 0, stream>>>(pa, flags);

  // merged conversions: biases/attn vectors + the 6 weight matrices
  CvtArgs ca;
  TArgs ta;
  int cvtblk = 0, tblk = 0;
  {
    struct { int idx; __bf16* out; int n; } cv[7] = {
      {4, bpb, 256}, {6, asb, 384}, {7, adb, 384}, {8, bgatb, 384},
      {10, bg0b, 64}, {12, bg1b, 64}, {15, bab, 64},
    };
    for (int k = 0; k < 7; k++) {
      ca.s[k].in = d_in[cv[k].idx]; ca.s[k].out = cv[k].out; ca.s[k].n = cv[k].n;
      ca.s[k].flagidx = cv[k].idx; ca.s[k].blk0 = cvtblk;
      cvtblk += (cv[k].n + 255) / 256;
    }
    struct { int idx; __bf16* out; int R; int C; } tv[6] = {
      {3,  Wp_t,             256, 256},
      {5,  Wgat_t,           256, 384},
      {9,  Wg01_t,           256, 64},
      {11, Wg01_t + 64 * 256, 256, 64},
      {13, Warma_t,          384, 64},
      {14, Warma_t + 64 * 384, 384, 64},
    };
    for (int k = 0; k < 6; k++) {
      ta.s[k].in = d_in[tv[k].idx]; ta.s[k].out = tv[k].out;
      ta.s[k].R = tv[k].R; ta.s[k].C = tv[k].C;
      ta.s[k].flagidx = tv[k].idx; ta.s[k].blk0 = tblk;
      tblk += ((tv[k].R + 31) / 32) * ((tv[k].C + 31) / 32);
    }
    k_cvt_merged<<<dim3(cvtblk + tblk), tb, 0, stream>>>(ca, cvtblk, ta, flags);
  }

  // CSR by dst + degree norms (parallel coalesced scan)
  const int NBLK = (NN + 255) / 256;  // 79
  k_count<<<dim3((EE + 255) / 256), tb, 0, stream>>>(ei, d_in[2], flags, deg, wdeg);
  k_scan1<<<dim3(NBLK), tb, 0, stream>>>(deg, bsum);
  k_scan2<<<dim3(NBLK), tb, 0, stream>>>(deg, bsum, wdeg, rowstart, dgcn, darma);
  k_fill<<<dim3((EE + 255) / 256), tb, 0, stream>>>(ei, d_in[2], flags, rowstart, cursor, csr_src, csr_w);

  const int MB64 = (NN + 63) / 64;  // 313
  // h = x @ Wp + bp   (N=256 -> 2 col-128 blocks)
  gemm64<true ><<<dim3(MB64, 2), tb, 0, stream>>>(d_in[0], &flags[0], Wp_t, bpb,
                                                  h, 256, 256, nullptr, 0, NN, 256);
  // fused: xwb = h @ Wgat (cols 0..383), xwgb = h @ Wgcn01 (cols 384..511); N=512 -> 4 blocks
  gemm64<false><<<dim3(MB64, 4), tb, 0, stream>>>(h, &flags[30], Wcat_t, nullptr,
                                                  xwb, 384, 384, xwgb, 128, NN, 256);
  k_alar_w<<<dim3((NN * NH + 3) / 4), tb, 0, stream>>>(xwb, asb, adb, al, ar);
  // h dead; h1b overwrites region A
  k_gat2<<<dim3(NN / 4), tb, 0, stream>>>(xwb, al, ar, rowstart, csr_src, bgatb, h1b, out);
  // xwb dead; trb overwrites region B   (N=128 -> 1 block)
  gemm64<false><<<dim3(MB64, 1), tb, 0, stream>>>(h1b, &flags[30], Warma_t, nullptr,
                                                  trb, 128, 128, nullptr, 0, NN, 384);
  k_gcnarma2<<<dim3(NN / 4), tb, 0, stream>>>(xwgb, trb, rowstart, csr_src, csr_w,
                                              dgcn, darma, bg0b, bg1b, bab, out);
}

// Round 7
// 295.767 us; speedup vs baseline: 1.2032x; 1.0014x over previous
//
#include <hip/hip_runtime.h>

// R19: gather passes restructured by dependency. GCN aggregation (needs xwgb,
// ready pre-GAT) fused INTO the GAT gather (k_gatgcn: R12 loop + 2 extra
// narrow loads/edge, shared CSR staging/barriers). ARMA gather (needs trb,
// ready post-GEMM4) isolated in k_arma: 1 load/edge, 8-edge unroll with
// padded staging (R15-proven discipline). Rest verbatim R18 (296.2us).

#define NN 20000
#define EE 320000
#define GATD 384
#define NH 6
#define OUTD 64
#define ODIM 576

typedef __bf16 bf16_8 __attribute__((ext_vector_type(8)));
typedef float f32_4 __attribute__((ext_vector_type(4)));

__device__ __forceinline__ float lrelu(float x, float s) { return x > 0.f ? x : s * x; }

__device__ __forceinline__ float loadf(const void* p, size_t i, int f32) {
  return f32 ? ((const float*)p)[i] : (float)((const __bf16*)p)[i];
}

// ---------- fused dtype probes ----------
struct ProbeArgs {
  const void* ptr[15];
  int cnt[15];
  int flagidx[15];
  const int* ei;
};
__global__ void k_probe_all(ProbeArgs a, int* __restrict__ flags) {
  __shared__ int cnt;
  if (threadIdx.x == 0) cnt = 0;
  __syncthreads();
  int b = blockIdx.x;
  if (b < 15) {
    const unsigned short* u = (const unsigned short*)a.ptr[b];
    int m = a.cnt[b] < 2048 ? a.cnt[b] : 2048;
    int c = 0;
    for (int i = threadIdx.x; i < m; i += 256) {
      float v = __uint_as_float(((unsigned int)u[i]) << 16);
      if (!(fabsf(v) < 1e4f)) c++;
    }
    if (c) atomicAdd(&cnt, c);
    __syncthreads();
    if (threadIdx.x == 0) flags[a.flagidx[b]] = (cnt > m / 16) ? 1 : 0;
  } else {
    int c = 0;
    for (int i = threadIdx.x; i < 1024; i += 256)
      if (a.ei[2 * i + 1] != 0) c++;
    if (c) atomicAdd(&cnt, c);
    __syncthreads();
    if (threadIdx.x == 0) flags[16] = (cnt <= 2) ? 1 : 0;
  }
}

// ---------- merged small conversions + weight cvt/transpose ----------
struct CvtSeg { const void* in; __bf16* out; int n; int flagidx; int blk0; };
struct CvtArgs { CvtSeg s[7]; };
struct TSeg { const void* in; __bf16* out; int R; int C; int flagidx; int blk0; };
struct TArgs { TSeg s[6]; };
__global__ void k_cvt_merged(CvtArgs ca, int ncvtblk, TArgs ta, const int* __restrict__ flags) {
  if ((int)blockIdx.x < ncvtblk) {
    int b = blockIdx.x;
    int k = 0;
    while (k + 1 < 7 && ca.s[k + 1].blk0 <= b) k++;
    const CvtSeg sg = ca.s[k];
    int i = (b - sg.blk0) * 256 + threadIdx.x;
    if (i >= sg.n) return;
    sg.out[i] = flags[sg.flagidx] ? (__bf16)((const float*)sg.in)[i] : ((const __bf16*)sg.in)[i];
    return;
  }
  __shared__ float t[32][33];
  int b = blockIdx.x - ncvtblk;
  int k = 0;
  while (k + 1 < 6 && ta.s[k + 1].blk0 <= b) k++;
  const TSeg sg = ta.s[k];
  int f32 = flags[sg.flagidx];
  int tpx = (sg.C + 31) >> 5;
  int lt = b - sg.blk0;
  int c0 = (lt % tpx) * 32, r0 = (lt / tpx) * 32;
  int tid = threadIdx.x;
  for (int idx = tid; idx < 1024; idx += 256) {
    int r = idx >> 5, c = idx & 31;
    if (r0 + r < sg.R && c0 + c < sg.C)
      t[r][c] = loadf(sg.in, (size_t)(r0 + r) * sg.C + (c0 + c), f32);
  }
  __syncthreads();
  for (int idx = tid; idx < 1024; idx += 256) {
    int r = idx >> 5, c = idx & 31;
    if (c0 + r < sg.C && r0 + c < sg.R)
      sg.out[(size_t)(c0 + r) * sg.R + (r0 + c)] = (__bf16)t[c][r];
  }
}

// ---------- CSR build ----------
__global__ void k_count(const int* __restrict__ ei, const void* __restrict__ ew,
                        const int* __restrict__ flags,
                        int* __restrict__ deg, float* __restrict__ wdeg) {
  int e = blockIdx.x * 256 + threadIdx.x;
  if (e >= EE) return;
  int sh = flags[16];
  int d = ei[(size_t)(EE + e) << sh];
  atomicAdd(&deg[d], 1);
  atomicAdd(&wdeg[d], loadf(ew, e, flags[2]));
}

// parallel coalesced scan, phase 1: per-block sums of deg
__global__ __launch_bounds__(256) void k_scan1(const int* __restrict__ deg,
                                               int* __restrict__ bsum) {
  int i = blockIdx.x * 256 + threadIdx.x;
  int v = (i < NN) ? deg[i] : 0;
  for (int off = 32; off; off >>= 1) v += __shfl_xor(v, off);
  __shared__ int ws[4];
  if ((threadIdx.x & 63) == 0) ws[threadIdx.x >> 6] = v;
  __syncthreads();
  if (threadIdx.x == 0) bsum[blockIdx.x] = ws[0] + ws[1] + ws[2] + ws[3];
}

// phase 2: base reduce + in-block shuffle scan + rowstart + dinv tail
__global__ __launch_bounds__(256) void k_scan2(const int* __restrict__ deg,
    const int* __restrict__ bsum, const float* __restrict__ wdeg,
    int* __restrict__ rowstart, float* __restrict__ dg, float* __restrict__ da) {
  int b = blockIdx.x;
  int tid = threadIdx.x;
  int lane = tid & 63, wv = tid >> 6;
  int i = b * 256 + tid;
  __shared__ int red[4];
  __shared__ int wsum2[4];
  __shared__ int sbase;
  {
    int v = (tid < b) ? bsum[tid] : 0;
    for (int off = 32; off; off >>= 1) v += __shfl_xor(v, off);
    if (lane == 0) red[wv] = v;
    __syncthreads();
    if (tid == 0) sbase = red[0] + red[1] + red[2] + red[3];
    __syncthreads();
  }
  int v = (i < NN) ? deg[i] : 0;
  int run = v;
  for (int off = 1; off < 64; off <<= 1) {
    int u = __shfl_up(run, off);
    if (lane >= off) run += u;
  }
  if (lane == 63) wsum2[wv] = run;
  __syncthreads();
  int wb = 0;
#pragma unroll
  for (int w = 0; w < 4; w++) { int x = wsum2[w]; if (w < wv) wb += x; }
  int excl = sbase + wb + run - v;
  if (i < NN) rowstart[i] = excl;
  if (i == NN - 1) rowstart[NN] = excl + v;
  if (i < NN) {
    float w = wdeg[i];
    dg[i] = rsqrtf(w + 1.0f);
    da[i] = w > 0.f ? rsqrtf(w) : 0.f;
  }
}

__global__ void k_fill(const int* __restrict__ ei, const void* __restrict__ ew,
                       const int* __restrict__ flags, const int* __restrict__ rowstart,
                       int* __restrict__ cursor,
                       int* __restrict__ csr_src, float* __restrict__ csr_w) {
  int e = blockIdx.x * 256 + threadIdx.x;
  if (e >= EE) return;
  int sh = flags[16];
  int d = ei[(size_t)(EE + e) << sh];
  int s = ei[(size_t)e << sh];
  int pos = rowstart[d] + atomicAdd(&cursor[d], 1);
  csr_src[pos] = s;
  csr_w[pos] = loadf(ew, e, flags[2]);
}

// ---------- MFMA GEMM: 64x128 tile, dual output ---------- (R16/R18 verbatim)
template<bool HAS_BIAS>
__global__ __launch_bounds__(256) void gemm64(const void* __restrict__ A,
    const int* __restrict__ aflag, const __bf16* __restrict__ Bt,
    const __bf16* __restrict__ bias,
    __bf16* __restrict__ C1, int n1, int ldc1,
    __bf16* __restrict__ C2, int ldc2,
    int M, int K) {
  __shared__ __bf16 Al[64][40];
  __shared__ __bf16 Bl[128][40];
  int a32 = *aflag;
  int tid = threadIdx.x;
  int w = tid >> 6, lane = tid & 63;
  int quad = lane >> 4, r = lane & 15;
  int row0 = blockIdx.x * 64, col0 = blockIdx.y * 128;
  f32_4 acc[4][2] = {};
  int srow = tid >> 2;
  int koff = (tid & 3) * 8;
  int brow = tid >> 1;
  int bko  = (tid & 1) * 16;
  for (int kt = 0; kt < K; kt += 32) {
    int arow = row0 + srow;
    if (a32) {
      float4 a0 = {0.f, 0.f, 0.f, 0.f}, a1 = {0.f, 0.f, 0.f, 0.f};
      if (arow < M) {
        const float* ap = (const float*)A + (size_t)arow * K + kt + koff;
        a0 = *(const float4*)ap;
        a1 = *(const float4*)(ap + 4);
      }
      bf16_8 t;
      t[0] = (__bf16)a0.x; t[1] = (__bf16)a0.y; t[2] = (__bf16)a0.z; t[3] = (__bf16)a0.w;
      t[4] = (__bf16)a1.x; t[5] = (__bf16)a1.y; t[6] = (__bf16)a1.z; t[7] = (__bf16)a1.w;
      *(bf16_8*)(&Al[srow][koff]) = t;
    } else {
      float4 av = {0.f, 0.f, 0.f, 0.f};
      if (arow < M) av = *(const float4*)((const __bf16*)A + (size_t)arow * K + kt + koff);
      *(float4*)(&Al[srow][koff]) = av;
    }
    const __bf16* bp = Bt + (size_t)(col0 + brow) * K + kt + bko;
    *(float4*)(&Bl[brow][bko])     = *(const float4*)bp;
    *(float4*)(&Bl[brow][bko + 8]) = *(const float4*)(bp + 8);
    __syncthreads();
    bf16_8 bfrag0 = *(const bf16_8*)(&Bl[w * 16 + r][quad * 8]);
    bf16_8 bfrag1 = *(const bf16_8*)(&Bl[64 + w * 16 + r][quad * 8]);
#pragma unroll
    for (int mt = 0; mt < 4; mt++) {
      bf16_8 afrag = *(const bf16_8*)(&Al[mt * 16 + r][quad * 8]);
      acc[mt][0] = __builtin_amdgcn_mfma_f32_16x16x32_bf16(afrag, bfrag0, acc[mt][0], 0, 0, 0);
      acc[mt][1] = __builtin_amdgcn_mfma_f32_16x16x32_bf16(afrag, bfrag1, acc[mt][1], 0, 0, 0);
    }
    __syncthreads();
  }
  __bf16* Cp; int ldc; int cbase;
  if (col0 < n1) { Cp = C1; ldc = ldc1; cbase = col0; }
  else           { Cp = C2; ldc = ldc2; cbase = col0 - n1; }
  int cc0 = cbase + w * 16 + r;
  int cc1 = cbase + 64 + w * 16 + r;
  float bv0 = HAS_BIAS ? (float)bias[col0 + w * 16 + r] : 0.0f;
  float bv1 = HAS_BIAS ? (float)bias[col0 + 64 + w * 16 + r] : 0.0f;
#pragma unroll
  for (int mt = 0; mt < 4; mt++) {
#pragma unroll
    for (int rr = 0; rr < 4; rr++) {
      int crow = row0 + mt * 16 + quad * 4 + rr;
      if (crow < M) {
        Cp[(size_t)crow * ldc + cc0] = (__bf16)(acc[mt][0][rr] + bv0);
        Cp[(size_t)crow * ldc + cc1] = (__bf16)(acc[mt][1][rr] + bv1);
      }
    }
  }
}

// ---------- attention logits: wave per (node,head) ---------- (R12 verbatim)
__global__ void k_alar_w(const __bf16* __restrict__ xwb, const __bf16* __restrict__ as_,
                         const __bf16* __restrict__ ad_,
                         float* __restrict__ al, float* __restrict__ ar) {
  int p = blockIdx.x * 4 + (threadIdx.x >> 6);
  int lane = threadIdx.x & 63;
  if (p >= NN * NH) return;
  int i = p / NH, h = p - i * NH;
  float xv = (float)xwb[(size_t)i * GATD + h * OUTD + lane];
  float s1 = xv * (float)as_[h * OUTD + lane];
  float s2 = xv * (float)ad_[h * OUTD + lane];
  for (int off = 32; off; off >>= 1) { s1 += __shfl_xor(s1, off); s2 += __shfl_xor(s2, off); }
  if (lane == 0) { al[p] = s1; ar[p] = s2; }
}

// ---------- fused GAT + GCN0/1: wave per node, single CSR pass ----------
// R12 gat loop + 2 extra narrow loads/edge (xwgb) + wg staging. GCN output
// written to out[384:512]; ARMA moved to k_arma (needs trb, post-GEMM4).
__global__ __launch_bounds__(256) void k_gatgcn(const __bf16* __restrict__ xwb,
    const __bf16* __restrict__ xwgb,
    const float* __restrict__ al, const float* __restrict__ ar,
    const int* __restrict__ rowstart, const int* __restrict__ csr_src,
    const float* __restrict__ csr_w, const float* __restrict__ dgcn,
    const __bf16* __restrict__ bgat, const __bf16* __restrict__ b0,
    const __bf16* __restrict__ b1,
    __bf16* __restrict__ h1b, float* __restrict__ out) {
  int wv = threadIdx.x >> 6, lane = threadIdx.x & 63;
  int i = blockIdx.x * 4 + wv;           // NN % 4 == 0
  __shared__ int   src_sh[4][64];
  __shared__ float ex_sh[4][64][NH];
  __shared__ float wg_sh[4][64];
  __shared__ int   mc_sh[4];
  int e0 = rowstart[i], e1 = rowstart[i + 1];
  if (lane == 0) mc_sh[wv] = (e1 - e0 + 63) >> 6;
  float arv[NH], exs[NH], acc[NH], denp[NH];
#pragma unroll
  for (int h = 0; h < NH; h++) arv[h] = ar[i * NH + h];
#pragma unroll
  for (int h = 0; h < NH; h++) {
    float e = lrelu(al[i * NH + h] + arv[h], 0.2f);
    exs[h] = __expf(e);                  // self-loop weight
    acc[h] = exs[h] * (float)xwb[(size_t)i * GATD + h * OUTD + lane];
    denp[h] = 0.f;
  }
  float g0 = 0.f, g1 = 0.f;
  __syncthreads();
  int mch = max(max(mc_sh[0], mc_sh[1]), max(mc_sh[2], mc_sh[3]));
  for (int c = 0; c < mch; c++) {
    if (c) __syncthreads();
    int base = e0 + c * 64;
    int cnt = e1 - base; cnt = cnt < 0 ? 0 : (cnt > 64 ? 64 : cnt);
    if (lane < cnt) {
      int eidx = base + lane;
      int s = csr_src[eidx];
      src_sh[wv][lane] = s;
      wg_sh[wv][lane] = dgcn[s] * csr_w[eidx];
#pragma unroll
      for (int h = 0; h < NH; h++) {
        float ex = __expf(lrelu(al[s * NH + h] + arv[h], 0.2f));
        ex_sh[wv][lane][h] = ex;
        denp[h] += ex;
      }
    }
    __syncthreads();
    int j = 0;
    for (; j + 2 <= cnt; j += 2) {
      int s0 = src_sh[wv][j], s1 = src_sh[wv][j + 1];
      const __bf16* r0 = xwb + (size_t)s0 * GATD + lane;
      const __bf16* r1 = xwb + (size_t)s1 * GATD + lane;
      const __bf16* p0 = xwgb + (size_t)s0 * 128;
      const __bf16* p1 = xwgb + (size_t)s1 * 128;
      float x0[NH], x1[NH];
#pragma unroll
      for (int h = 0; h < NH; h++) { x0[h] = (float)r0[h * OUTD]; x1[h] = (float)r1[h * OUTD]; }
      float y00 = (float)p0[lane], y01 = (float)p0[lane + 64];
      float y10 = (float)p1[lane], y11 = (float)p1[lane + 64];
      float wg0 = wg_sh[wv][j], wg1 = wg_sh[wv][j + 1];
#pragma unroll
      for (int h = 0; h < NH; h++)
        acc[h] += ex_sh[wv][j][h] * x0[h] + ex_sh[wv][j + 1][h] * x1[h];
      g0 += wg0 * y00 + wg1 * y10;
      g1 += wg0 * y01 + wg1 * y11;
    }
    if (j < cnt) {
      int s0 = src_sh[wv][j];
      const __bf16* r0 = xwb + (size_t)s0 * GATD + lane;
      const __bf16* p0 = xwgb + (size_t)s0 * 128;
      float wg0 = wg_sh[wv][j];
#pragma unroll
      for (int h = 0; h < NH; h++) acc[h] += ex_sh[wv][j][h] * (float)r0[h * OUTD];
      g0 += wg0 * (float)p0[lane];
      g1 += wg0 * (float)p0[lane + 64];
    }
  }
#pragma unroll
  for (int h = 0; h < NH; h++) {
    float d = denp[h];
    for (int off = 32; off; off >>= 1) d += __shfl_xor(d, off);
    d += exs[h];
    float v = acc[h] / d + (float)bgat[h * OUTD + lane];
    v = lrelu(v, 0.01f);
    h1b[(size_t)i * GATD + h * OUTD + lane] = (__bf16)v;
    out[(size_t)i * ODIM + h * OUTD + lane] = tanhf(v);
  }
  float di = dgcn[i];
  float v0 = lrelu(di * g0 + di * di * (float)xwgb[(size_t)i * 128 + lane] + (float)b0[lane], 0.01f);
  float v1 = lrelu(di * g1 + di * di * (float)xwgb[(size_t)i * 128 + 64 + lane] + (float)b1[lane], 0.01f);
  out[(size_t)i * ODIM + 384 + lane] = tanhf(v0);
  out[(size_t)i * ODIM + 448 + lane] = tanhf(v1);
}

// ---------- ARMA gather: wave per node, 8-edge unroll, padded staging ----------
__global__ __launch_bounds__(256) void k_arma(const __bf16* __restrict__ trb,
    const int* __restrict__ rowstart, const int* __restrict__ csr_src,
    const float* __restrict__ csr_w, const float* __restrict__ darma,
    const __bf16* __restrict__ ba, float* __restrict__ out) {
  int wv = threadIdx.x >> 6, lane = threadIdx.x & 63;
  int i = blockIdx.x * 4 + wv;
  __shared__ __attribute__((aligned(16))) int   src_sh[4][64];
  __shared__ __attribute__((aligned(16))) float wa_sh[4][64];
  __shared__ int mc_sh[4];
  int e0 = rowstart[i], e1 = rowstart[i + 1];
  if (lane == 0) mc_sh[wv] = (e1 - e0 + 63) >> 6;
  __syncthreads();
  int mch = max(max(mc_sh[0], mc_sh[1]), max(mc_sh[2], mc_sh[3]));
  float aa = 0.f;
  for (int c = 0; c < mch; c++) {
    if (c) __syncthreads();
    int base = e0 + c * 64;
    int cnt = e1 - base; cnt = cnt < 0 ? 0 : (cnt > 64 ? 64 : cnt);
    int s = i; float wav = 0.f;           // padding: (src=i, w=0) contributes 0
    if (lane < cnt) {
      int eidx = base + lane;
      s = csr_src[eidx];
      wav = darma[s] * csr_w[eidx];
    }
    src_sh[wv][lane] = s;
    wa_sh[wv][lane] = wav;
    __syncthreads();
    int cntp = (cnt + 7) & ~7;
    for (int j = 0; j < cntp; j += 8) {
      int4 sa = *(const int4*)&src_sh[wv][j];
      int4 sb = *(const int4*)&src_sh[wv][j + 4];
      int sq[8] = {sa.x, sa.y, sa.z, sa.w, sb.x, sb.y, sb.z, sb.w};
      float tq[8];
#pragma unroll
      for (int q = 0; q < 8; q++)
        tq[q] = (float)trb[(size_t)sq[q] * 128 + lane];
      float4 wa0 = *(const float4*)&wa_sh[wv][j];
      float4 wa1 = *(const float4*)&wa_sh[wv][j + 4];
      float waq[8] = {wa0.x, wa0.y, wa0.z, wa0.w, wa1.x, wa1.y, wa1.z, wa1.w};
#pragma unroll
      for (int q = 0; q < 8; q++) aa += waq[q] * tq[q];
    }
  }
  float va = darma[i] * aa + (float)trb[(size_t)i * 128 + 64 + lane] + (float)ba[lane];
  va = fmaxf(va, 0.f);
  out[(size_t)i * ODIM + 512 + lane] = tanhf(va);
}

extern "C" void kernel_launch(void* const* d_in, const int* in_sizes, int n_in,
                              void* d_out, int out_size, void* d_ws, size_t ws_size,
                              hipStream_t stream) {
  const int* ei = (const int*)d_in[1];
  float* out = (float*)d_out;

  char* ws = (char*)d_ws;
  size_t off = 0;
  auto alloc = [&](size_t bytes) -> void* {
    void* p = ws + off;
    off += (bytes + 255) & ~(size_t)255;
    return p;
  };
  int*    flags    = (int*)alloc(32 * 4);
  int*    deg      = (int*)alloc((size_t)3 * NN * 4);
  int*    cursor   = deg + NN;
  float*  wdeg     = (float*)(deg + 2 * NN);
  int*    bsum     = (int*)alloc(128 * 4);
  int*    rowstart = (int*)alloc((size_t)(NN + 1) * 4);
  int*    csr_src  = (int*)alloc((size_t)EE * 4);
  float*  csr_w    = (float*)alloc((size_t)EE * 4);
  float*  dgcn     = (float*)alloc((size_t)NN * 4);
  float*  darma    = (float*)alloc((size_t)NN * 4);
  float*  al       = (float*)alloc((size_t)NN * NH * 4);
  float*  ar       = (float*)alloc((size_t)NN * NH * 4);
  __bf16* bpb   = (__bf16*)alloc(256 * 2);
  __bf16* asb   = (__bf16*)alloc(384 * 2);
  __bf16* adb   = (__bf16*)alloc(384 * 2);
  __bf16* bgatb = (__bf16*)alloc(384 * 2);
  __bf16* bg0b  = (__bf16*)alloc(64 * 2);
  __bf16* bg1b  = (__bf16*)alloc(64 * 2);
  __bf16* bab   = (__bf16*)alloc(64 * 2);
  __bf16* Wp_t    = (__bf16*)alloc(256 * 256 * 2);
  __bf16* Wcat_t  = (__bf16*)alloc((size_t)(384 + 128) * 256 * 2);
  __bf16* Wgat_t  = Wcat_t;
  __bf16* Wg01_t  = Wcat_t + (size_t)384 * 256;
  __bf16* Warma_t = (__bf16*)alloc(128 * 384 * 2);
  char* regA = (char*)alloc((size_t)NN * GATD * 2);
  __bf16* h   = (__bf16*)regA;   // dead after fused gemm
  __bf16* h1b = (__bf16*)regA;
  char* regB = (char*)alloc((size_t)NN * GATD * 2);
  __bf16* xwb = (__bf16*)regB;   // dead after k_gatgcn
  __bf16* trb = (__bf16*)regB;
  __bf16* xwgb = (__bf16*)alloc((size_t)NN * 128 * 2);
  (void)ws_size; (void)in_sizes; (void)n_in; (void)out_size;

  hipMemsetAsync(ws, 0, 256 + (size_t)3 * NN * 4, stream);

  dim3 tb(256);
  // fused probes
  ProbeArgs pa;
  const int pidx[15] = {0, 2, 3, 4, 5, 6, 7, 8, 9, 10, 11, 12, 13, 14, 15};
  const int pcnt[15] = {NN * 256, EE, 256 * 256, 256, 256 * 384, NH * OUTD, NH * OUTD,
                        NH * OUTD, 256 * 64, 64, 256 * 64, 64, GATD * OUTD, GATD * OUTD, 64};
  for (int k = 0; k < 15; k++) { pa.ptr[k] = d_in[pidx[k]]; pa.cnt[k] = pcnt[k]; pa.flagidx[k] = pidx[k]; }
  pa.ei = ei;
  k_probe_all<<<dim3(16), tb, 0, stream>>>(pa, flags);

  // merged conversions
  CvtArgs ca;
  TArgs ta;
  int cvtblk = 0, tblk = 0;
  {
    struct { int idx; __bf16* out; int n; } cv[7] = {
      {4, bpb, 256}, {6, asb, 384}, {7, adb, 384}, {8, bgatb, 384},
      {10, bg0b, 64}, {12, bg1b, 64}, {15, bab, 64},
    };
    for (int k = 0; k < 7; k++) {
      ca.s[k].in = d_in[cv[k].idx]; ca.s[k].out = cv[k].out; ca.s[k].n = cv[k].n;
      ca.s[k].flagidx = cv[k].idx; ca.s[k].blk0 = cvtblk;
      cvtblk += (cv[k].n + 255) / 256;
    }
    struct { int idx; __bf16* out; int R; int C; } tv[6] = {
      {3,  Wp_t,             256, 256},
      {5,  Wgat_t,           256, 384},
      {9,  Wg01_t,           256, 64},
      {11, Wg01_t + 64 * 256, 256, 64},
      {13, Warma_t,          384, 64},
      {14, Warma_t + 64 * 384, 384, 64},
    };
    for (int k = 0; k < 6; k++) {
      ta.s[k].in = d_in[tv[k].idx]; ta.s[k].out = tv[k].out;
      ta.s[k].R = tv[k].R; ta.s[k].C = tv[k].C;
      ta.s[k].flagidx = tv[k].idx; ta.s[k].blk0 = tblk;
      tblk += ((tv[k].R + 31) / 32) * ((tv[k].C + 31) / 32);
    }
    k_cvt_merged<<<dim3(cvtblk + tblk), tb, 0, stream>>>(ca, cvtblk, ta, flags);
  }

  // CSR by dst + degree norms (parallel coalesced scan)
  const int NBLK = (NN + 255) / 256;  // 79
  k_count<<<dim3((EE + 255) / 256), tb, 0, stream>>>(ei, d_in[2], flags, deg, wdeg);
  k_scan1<<<dim3(NBLK), tb, 0, stream>>>(deg, bsum);
  k_scan2<<<dim3(NBLK), tb, 0, stream>>>(deg, bsum, wdeg, rowstart, dgcn, darma);
  k_fill<<<dim3((EE + 255) / 256), tb, 0, stream>>>(ei, d_in[2], flags, rowstart, cursor, csr_src, csr_w);

  const int MB64 = (NN + 63) / 64;  // 313
  // h = x @ Wp + bp   (N=256 -> 2 col-128 blocks)
  gemm64<true ><<<dim3(MB64, 2), tb, 0, stream>>>(d_in[0], &flags[0], Wp_t, bpb,
                                                  h, 256, 256, nullptr, 0, NN, 256);
  // fused: xwb = h @ Wgat (cols 0..383), xwgb = h @ Wgcn01 (cols 384..511)
  gemm64<false><<<dim3(MB64, 4), tb, 0, stream>>>(h, &flags[30], Wcat_t, nullptr,
                                                  xwb, 384, 384, xwgb, 128, NN, 256);
  k_alar_w<<<dim3((NN * NH + 3) / 4), tb, 0, stream>>>(xwb, asb, adb, al, ar);
  // h dead; h1b overwrites region A. GAT + GCN0/1 in one CSR pass.
  k_gatgcn<<<dim3(NN / 4), tb, 0, stream>>>(xwb, xwgb, al, ar, rowstart, csr_src,
                                            csr_w, dgcn, bgatb, bg0b, bg1b, h1b, out);
  // xwb dead; trb overwrites region B   (N=128 -> 1 block)
  gemm64<false><<<dim3(MB64, 1), tb, 0, stream>>>(h1b, &flags[30], Warma_t, nullptr,
                                                  trb, 128, 128, nullptr, 0, NN, 384);
  k_arma<<<dim3(NN / 4), tb, 0, stream>>>(trb, rowstart, csr_src, csr_w,
                                          darma, bab, out);
}